// Round 12
// baseline (277.943 us; speedup 1.0000x reference)
//
#include <hip/hip_runtime.h>
#include <cmath>

#define DCOL 768
#define D4C 192           // DCOL/4 float4 columns
#define KCH 96            // DCOL/8
#define FTHREADS 384

typedef __attribute__((ext_vector_type(8))) short bf16x8;
typedef __attribute__((ext_vector_type(4))) float f32x4;

__device__ __forceinline__ short f2bf(float f) {
    return (short)(__builtin_bit_cast(unsigned, f) >> 16);
}
__device__ __forceinline__ float bf2f(short s) {
    unsigned u = ((unsigned)(unsigned short)s) << 16;
    return __builtin_bit_cast(float, u);
}

__device__ __forceinline__ int lower_bound_i(const int* __restrict__ arr, int n, int val) {
    int lo = 0, hi = n;
    while (lo < hi) {
        int mid = (lo + hi) >> 1;
        if (arr[mid] < val) lo = mid + 1; else hi = mid;
    }
    return lo;
}

__device__ __forceinline__ float4 f4add(float4 a, float4 b) {
    a.x += b.x; a.y += b.y; a.z += b.z; a.w += b.w; return a;
}

// ---- reshape weights: fp32 src[k][j] -> bf16 W3[((jg*KCH + kk)*64 + (j&63))*8 + ki]
__global__ void reshape_w(const float* __restrict__ src0, short* __restrict__ dst0,
                          const float* __restrict__ src1, short* __restrict__ dst1) {
    const float* __restrict__ src = blockIdx.z ? src1 : src0;
    short* __restrict__ dst = blockIdx.z ? dst1 : dst0;
    int t = blockIdx.x * 256 + threadIdx.x;     // [0, 12*KCH*64)
    int lane = t & 63;
    int kk8 = (t >> 6) % KCH;
    int jg = t / (KCH * 64);
    int j = jg * 64 + lane;
    bf16x8 w;
    #pragma unroll
    for (int ki = 0; ki < 8; ++ki)
        w[ki] = f2bf(src[(size_t)(kk8 * 8 + ki) * DCOL + j]);
    *(bf16x8*)(dst + (size_t)t * 8) = w;
}

// ---- dual GEMV dot: outputs j0 = wid*64+lane and j1 = j0+384; x loaded once ----
__device__ __forceinline__ void gemv_dot2(const short* __restrict__ W3,
                                          const float* __restrict__ xs,
                                          int wid, int lane, float& o0, float& o1) {
    const bf16x8* __restrict__ wp0 = (const bf16x8*)W3 + (size_t)wid * (KCH * 64) + lane;
    const bf16x8* __restrict__ wp1 = (const bf16x8*)W3 + (size_t)(wid + 6) * (KCH * 64) + lane;
    float a0 = 0.f, a1 = 0.f;
    #pragma unroll 4
    for (int kk = 0; kk < KCH; ++kk) {
        bf16x8 w0 = wp0[(size_t)kk * 64];
        bf16x8 w1 = wp1[(size_t)kk * 64];
        const float* xk = xs + kk * 8;
        float4 xa = *(const float4*)(xk);
        float4 xb = *(const float4*)(xk + 4);
        a0 += bf2f(w0[0]) * xa.x + bf2f(w0[1]) * xa.y + bf2f(w0[2]) * xa.z + bf2f(w0[3]) * xa.w
            + bf2f(w0[4]) * xb.x + bf2f(w0[5]) * xb.y + bf2f(w0[6]) * xb.z + bf2f(w0[7]) * xb.w;
        a1 += bf2f(w1[0]) * xa.x + bf2f(w1[1]) * xa.y + bf2f(w1[2]) * xa.z + bf2f(w1[3]) * xa.w
            + bf2f(w1[4]) * xb.x + bf2f(w1[5]) * xb.y + bf2f(w1[6]) * xb.z + bf2f(w1[7]) * xb.w;
    }
    o0 = a0; o1 = a1;
}

// ---- fused per-graph kernel, 384 threads (6 waves -> 4 blocks/CU) ----
// Streaming: thread = (c, rr), c = float4 col 0..191, rr = row phase 0..1.
// GEMV: thread t owns output cols t and t+384.
__global__ __launch_bounds__(FTHREADS, 6) void fused_kernel(
        const float4* __restrict__ feat4, const float* __restrict__ vn,
        const int* __restrict__ batch,
        const short* __restrict__ W3fc, const float* __restrict__ fcb,
        const short* __restrict__ W3p, const float* __restrict__ pb,
        float* __restrict__ out_feat, float* __restrict__ out_vn, int N) {
    __shared__ __align__(16) float part[2][DCOL];
    __shared__ __align__(16) float xbuf[DCOL];
    __shared__ __align__(16) float x2buf[DCOL];
    __shared__ __align__(16) float ybuf[DCOL];
    __shared__ int srange[2];

    const int g = blockIdx.x;
    const int t = threadIdx.x;
    if (t < 2) srange[t] = lower_bound_i(batch, N, g + t);
    __syncthreads();
    const int lo = srange[0], hi = srange[1];
    const int cnt = hi - lo;

    const int c = t % D4C;      // float4 column 0..191
    const int rr = t / D4C;     // 0..1

    // ---- phase 1: column sums; this thread does rows rr, rr+2, ... ----
    const float4* __restrict__ fp4 = feat4 + (size_t)lo * D4C + c;
    float4 a0 = {0,0,0,0}, a1 = {0,0,0,0}, a2 = {0,0,0,0}, a3 = {0,0,0,0};
    float4 a4 = {0,0,0,0}, a5 = {0,0,0,0}, a6 = {0,0,0,0}, a7 = {0,0,0,0};
    int k = rr;
    for (; k + 14 < cnt; k += 16) {
        float4 v0 = fp4[(size_t)(k +  0) * D4C];
        float4 v1 = fp4[(size_t)(k +  2) * D4C];
        float4 v2 = fp4[(size_t)(k +  4) * D4C];
        float4 v3 = fp4[(size_t)(k +  6) * D4C];
        float4 v4 = fp4[(size_t)(k +  8) * D4C];
        float4 v5 = fp4[(size_t)(k + 10) * D4C];
        float4 v6 = fp4[(size_t)(k + 12) * D4C];
        float4 v7 = fp4[(size_t)(k + 14) * D4C];
        a0 = f4add(a0, v0); a1 = f4add(a1, v1); a2 = f4add(a2, v2); a3 = f4add(a3, v3);
        a4 = f4add(a4, v4); a5 = f4add(a5, v5); a6 = f4add(a6, v6); a7 = f4add(a7, v7);
    }
    for (; k < cnt; k += 2) a0 = f4add(a0, fp4[(size_t)k * D4C]);
    float4 s = f4add(f4add(f4add(a0, a1), f4add(a2, a3)), f4add(f4add(a4, a5), f4add(a6, a7)));
    *(float4*)&part[rr][c * 4] = s;
    __syncthreads();

    // reduce across rr, scale, add vn -> xbuf (192 threads)
    if (t < D4C) {
        float4 p0 = *(const float4*)&part[0][t * 4];
        float4 p1 = *(const float4*)&part[1][t * 4];
        float4 ss = f4add(p0, p1);
        float scale = cnt > 0 ? (logf((float)cnt) / (float)cnt) : 0.f;
        float4 vnv = *(const float4*)(vn + (size_t)g * DCOL + t * 4);
        float4 x;
        x.x = ss.x * scale + vnv.x; x.y = ss.y * scale + vnv.y;
        x.z = ss.z * scale + vnv.z; x.w = ss.w * scale + vnv.w;
        *(float4*)&xbuf[t * 4] = x;
    }
    __syncthreads();

    // ---- phase 2: GEMV1  h = relu(x @ fcW + fcb); vn_new = vn + h ----
    const int wid = t >> 6, lane = t & 63;
    const int j0 = t, j1 = t + 384;
    float h0, h1;
    gemv_dot2(W3fc, xbuf, wid, lane, h0, h1);
    h0 = fmaxf(h0 + fcb[j0], 0.f);
    h1 = fmaxf(h1 + fcb[j1], 0.f);
    float vnn0 = vn[(size_t)g * DCOL + j0] + h0;
    float vnn1 = vn[(size_t)g * DCOL + j1] + h1;
    out_vn[(size_t)g * DCOL + j0] = vnn0;
    out_vn[(size_t)g * DCOL + j1] = vnn1;
    x2buf[j0] = vnn0;
    x2buf[j1] = vnn1;
    __syncthreads();

    // ---- phase 3: GEMV2  y = vn_new @ pW + pb ----
    float y0, y1;
    gemv_dot2(W3p, x2buf, wid, lane, y0, y1);
    ybuf[j0] = y0 + pb[j0];
    ybuf[j1] = y1 + pb[j1];
    __syncthreads();

    // ---- phase 4: re-read rows (L3-hot window) + add y, nt float4 stores ----
    float4 y4 = *(const float4*)&ybuf[c * 4];
    float* op = out_feat + (size_t)lo * DCOL + c * 4;
    k = rr;
    for (; k + 6 < cnt; k += 8) {
        float4 f0 = fp4[(size_t)(k + 0) * D4C];
        float4 f1 = fp4[(size_t)(k + 2) * D4C];
        float4 f2 = fp4[(size_t)(k + 4) * D4C];
        float4 f3 = fp4[(size_t)(k + 6) * D4C];
        f32x4 r0, r1, r2, r3;
        r0.x = f0.x + y4.x; r0.y = f0.y + y4.y; r0.z = f0.z + y4.z; r0.w = f0.w + y4.w;
        r1.x = f1.x + y4.x; r1.y = f1.y + y4.y; r1.z = f1.z + y4.z; r1.w = f1.w + y4.w;
        r2.x = f2.x + y4.x; r2.y = f2.y + y4.y; r2.z = f2.z + y4.z; r2.w = f2.w + y4.w;
        r3.x = f3.x + y4.x; r3.y = f3.y + y4.y; r3.z = f3.z + y4.z; r3.w = f3.w + y4.w;
        __builtin_nontemporal_store(r0, (f32x4*)(op + (size_t)(k + 0) * DCOL));
        __builtin_nontemporal_store(r1, (f32x4*)(op + (size_t)(k + 2) * DCOL));
        __builtin_nontemporal_store(r2, (f32x4*)(op + (size_t)(k + 4) * DCOL));
        __builtin_nontemporal_store(r3, (f32x4*)(op + (size_t)(k + 6) * DCOL));
    }
    for (; k < cnt; k += 2) {
        float4 f0 = fp4[(size_t)k * D4C];
        f32x4 r0;
        r0.x = f0.x + y4.x; r0.y = f0.y + y4.y; r0.z = f0.z + y4.z; r0.w = f0.w + y4.w;
        __builtin_nontemporal_store(r0, (f32x4*)(op + (size_t)k * DCOL));
    }
}

extern "C" void kernel_launch(void* const* d_in, const int* in_sizes, int n_in,
                              void* d_out, int out_size, void* d_ws, size_t ws_size,
                              hipStream_t stream) {
    const float* feat  = (const float*)d_in[0];
    const float* vn    = (const float*)d_in[1];
    const float* edge  = (const float*)d_in[2];
    const int*   batch = (const int*)d_in[3];
    const float* fcW   = (const float*)d_in[5];
    const float* fcb   = (const float*)d_in[6];
    const float* pW    = (const float*)d_in[7];
    const float* pb    = (const float*)d_in[8];

    const int D = in_sizes[6];            // 768
    const int N = in_sizes[0] / D;        // 100000
    const int B = in_sizes[1] / D;        // 1024
    const int edge_elems = in_sizes[2];   // B*DE

    float* out_feat = (float*)d_out;
    float* out_vn   = out_feat + (size_t)N * D;
    float* out_edge = out_vn + (size_t)B * D;

    char* ws = (char*)d_ws;
    short* W3fc = (short*)ws;                                 // [12*96*64*8] bf16
    short* W3p  = (short*)(ws + (size_t)12 * KCH * 64 * 8 * 2);

    // 0) reshape both weight matrices to the GEMV-coalesced bf16 layout
    dim3 rg(12 * KCH * 64 / 256, 1, 2);
    reshape_w<<<rg, 256, 0, stream>>>(fcW, W3fc, pW, W3p);

    // 1) fused pool + FC + project + broadcast-add (one block per graph)
    fused_kernel<<<B, FTHREADS, 0, stream>>>((const float4*)feat, vn, batch,
                                             W3fc, fcb, W3p, pb,
                                             out_feat, out_vn, N);

    // 2) edge passthrough
    hipMemcpyAsync(out_edge, edge, (size_t)edge_elems * sizeof(float),
                   hipMemcpyDeviceToDevice, stream);
}

// Round 13
// 182.567 us; speedup vs baseline: 1.5224x; 1.5224x over previous
//
#include <hip/hip_runtime.h>
#include <cmath>

#define THREADS 256
#define PCOLS 192         // 768 floats / 4 = 192 float4 columns
#define T_RESIDENT 72000  // feat rows < T kept L3-allocating (221 MB of 256 MB)

typedef __attribute__((ext_vector_type(8))) short bf16x8;
typedef __attribute__((ext_vector_type(4))) float f32x4;

__device__ __forceinline__ short f2bf(float f) {
    return (short)(__builtin_bit_cast(unsigned, f) >> 16);
}

typedef const __attribute__((address_space(1))) unsigned int* gas1_t;
typedef __attribute__((address_space(3))) unsigned int* las3_t;
__device__ __forceinline__ void gload16(const short* g, short* l) {
    __builtin_amdgcn_global_load_lds((gas1_t)g, (las3_t)l, 16, 0, 0);
}

__device__ __forceinline__ int lower_bound_i(const int* __restrict__ arr, int n, int val) {
    int lo = 0, hi = n;
    while (lo < hi) {
        int mid = (lo + hi) >> 1;
        if (arr[mid] < val) lo = mid + 1; else hi = mid;
    }
    return lo;
}

__device__ __forceinline__ float4 f4add(float4 a, float4 b) {
    a.x += b.x; a.y += b.y; a.z += b.z; a.w += b.w; return a;
}
__device__ __forceinline__ float4 f4fma(float4 a, float s, float4 b) {
    b.x += a.x * s; b.y += a.y * s; b.z += a.z * s; b.w += a.w * s; return b;
}

template <bool NT>
__device__ __forceinline__ float4 ldf4(const float4* p) {
    if constexpr (NT) {
        f32x4 v = __builtin_nontemporal_load((const f32x4*)p);
        float4 r; r.x = v.x; r.y = v.y; r.z = v.z; r.w = v.w; return r;
    } else {
        return *p;
    }
}

// -------- transpose+convert: dst[n][k] (bf16) = src[k][n] (fp32), square n --------
__global__ void transpose_bf16(const float* __restrict__ src0, short* __restrict__ dst0,
                               const float* __restrict__ src1, short* __restrict__ dst1,
                               int n) {
    const float* src = blockIdx.z ? src1 : src0;
    short* dst = blockIdx.z ? dst1 : dst0;
    __shared__ short tile[32][33];
    int bx = blockIdx.x * 32, by = blockIdx.y * 32;
    int tx = threadIdx.x, ty = threadIdx.y;  // 32 x 8
    #pragma unroll
    for (int i = 0; i < 32; i += 8)
        tile[ty + i][tx] = f2bf(src[(size_t)(by + ty + i) * n + bx + tx]);
    __syncthreads();
    #pragma unroll
    for (int i = 0; i < 32; i += 8)
        dst[(size_t)(bx + ty + i) * n + by + tx] = tile[tx][ty + i];
}

// ---------------- pool: x_bf[g] = bf16( seg_mean(feat)*log(cnt) + vn[g] ) --------
// Rows < Tres: normal loads (allocate/stay in L3); rows >= Tres: nt loads.
template <bool NT>
__device__ __forceinline__ void accum8(const float4* __restrict__ base, int a, int b, int D4, int t,
                                       float4& a0, float4& a1, float4& a2, float4& a3,
                                       float4& a4, float4& a5, float4& a6, float4& a7) {
    const float4* __restrict__ p = base + (size_t)a * D4 + t;
    int r = a;
    for (; r + 8 <= b; r += 8) {
        float4 v0 = ldf4<NT>(p + 0 * (size_t)D4);
        float4 v1 = ldf4<NT>(p + 1 * (size_t)D4);
        float4 v2 = ldf4<NT>(p + 2 * (size_t)D4);
        float4 v3 = ldf4<NT>(p + 3 * (size_t)D4);
        float4 v4 = ldf4<NT>(p + 4 * (size_t)D4);
        float4 v5 = ldf4<NT>(p + 5 * (size_t)D4);
        float4 v6 = ldf4<NT>(p + 6 * (size_t)D4);
        float4 v7 = ldf4<NT>(p + 7 * (size_t)D4);
        a0 = f4add(a0, v0); a1 = f4add(a1, v1); a2 = f4add(a2, v2); a3 = f4add(a3, v3);
        a4 = f4add(a4, v4); a5 = f4add(a5, v5); a6 = f4add(a6, v6); a7 = f4add(a7, v7);
        p += 8 * (size_t)D4;
    }
    for (; r < b; ++r) {
        a0 = f4add(a0, ldf4<NT>(p));
        p += D4;
    }
}

__global__ void pool_kernel(const float4* __restrict__ feat4, const float4* __restrict__ vn4,
                            const int* __restrict__ batch, short* __restrict__ xbf,
                            int N, int D4, int Tres) {
    int g = blockIdx.x;
    __shared__ int s_range[2];
    if (threadIdx.x < 2) s_range[threadIdx.x] = lower_bound_i(batch, N, g + (int)threadIdx.x);
    __syncthreads();
    int lo = s_range[0], hi = s_range[1];
    int cnt = hi - lo;
    float scale = (cnt > 0) ? (logf((float)cnt) / (float)cnt) : 0.f;

    int t = threadIdx.x;
    float4 a0 = {0,0,0,0}, a1 = {0,0,0,0}, a2 = {0,0,0,0}, a3 = {0,0,0,0};
    float4 a4 = {0,0,0,0}, a5 = {0,0,0,0}, a6 = {0,0,0,0}, a7 = {0,0,0,0};

    int m = hi < Tres ? hi : (lo > Tres ? lo : Tres);  // clamp(Tres, lo, hi)
    accum8<false>(feat4, lo, m, D4, t, a0, a1, a2, a3, a4, a5, a6, a7);
    accum8<true >(feat4, m, hi, D4, t, a0, a1, a2, a3, a4, a5, a6, a7);

    float4 s = f4add(f4add(f4add(a0, a1), f4add(a2, a3)), f4add(f4add(a4, a5), f4add(a6, a7)));
    float4 vnv = vn4[(size_t)g * D4 + t];
    float4 x = f4fma(s, scale, vnv);
    short4 o;
    o.x = f2bf(x.x); o.y = f2bf(x.y); o.z = f2bf(x.z); o.w = f2bf(x.w);
    *(short4*)(xbf + ((size_t)g * D4 + t) * 4) = o;
}

// ---------------- bf16-native MFMA GEMM ----------------
// out = [relu](A @ Wt^T + bias) [+ res];  A [M][K] bf16, Wt [Nn][K] bf16.
// BM=BN=64, BK=32; 4 waves, 2x2 16x16x32 frags each. LDS dbuf, chunk-XOR
// swizzle via pre-swizzled global_load_lds source. 4 ds_read_b128 + 4 MFMA
// per wave per K-step, zero conversions.
template <bool RELU, bool ADD_RES, bool WRITE_BF>
__global__ __launch_bounds__(256) void gemm_bf(const short* __restrict__ A,
        const short* __restrict__ Wt, const float* __restrict__ bias,
        const float* __restrict__ res, float* __restrict__ out,
        short* __restrict__ out_bf, int Nn, int K) {
    __shared__ short lds[2][2][64 * 32];
    const int tid = threadIdx.x;
    const int lane = tid & 63;
    const int wid = tid >> 6;
    const int wr = wid >> 1, wc = wid & 1;
    const int lrow = lane & 15;
    const int kg = lane >> 4;
    const int tileM = blockIdx.y * 64;
    const int tileN = blockIdx.x * 64;
    const int nk = K / 32;

    f32x4 acc[2][2] = {};

    const int srow = tid >> 2;
    const int sci = (tid & 3) ^ (srow & 3);

    #define STG(buf, kt) do {                                                    \
        short* La = lds[buf][0];                                                 \
        short* Lb = lds[buf][1];                                                 \
        gload16(A  + (size_t)(tileM + srow) * K + (kt) * 32 + sci * 8, La + tid * 8); \
        gload16(Wt + (size_t)(tileN + srow) * K + (kt) * 32 + sci * 8, Lb + tid * 8); \
    } while (0)

    STG(0, 0);
    __syncthreads();

    for (int kt = 0; kt < nk; ++kt) {
        if (kt + 1 < nk) STG((kt + 1) & 1, kt + 1);
        const short* La = lds[kt & 1][0];
        const short* Lb = lds[kt & 1][1];
        bf16x8 a[2], b[2];
        #pragma unroll
        for (int m = 0; m < 2; ++m) {
            int row = wr * 32 + m * 16 + lrow;
            a[m] = *(const bf16x8*)(La + row * 32 + ((kg ^ (row & 3)) * 8));
        }
        #pragma unroll
        for (int n = 0; n < 2; ++n) {
            int col = wc * 32 + n * 16 + lrow;
            b[n] = *(const bf16x8*)(Lb + col * 32 + ((kg ^ (col & 3)) * 8));
        }
        #pragma unroll
        for (int m = 0; m < 2; ++m)
            #pragma unroll
            for (int n = 0; n < 2; ++n)
                acc[m][n] = __builtin_amdgcn_mfma_f32_16x16x32_bf16(a[m], b[n], acc[m][n], 0, 0, 0);
        __syncthreads();
    }

    #pragma unroll
    for (int m = 0; m < 2; ++m) {
        #pragma unroll
        for (int n = 0; n < 2; ++n) {
            int col = tileN + wc * 32 + n * 16 + lrow;
            float bv = bias[col];
            #pragma unroll
            for (int r = 0; r < 4; ++r) {
                int row = tileM + wr * 32 + m * 16 + kg * 4 + r;
                float v = acc[m][n][r] + bv;
                if (RELU) v = fmaxf(v, 0.f);
                if (ADD_RES) v += res[(size_t)row * Nn + col];
                out[(size_t)row * Nn + col] = v;
                if (WRITE_BF) out_bf[(size_t)row * Nn + col] = f2bf(v);
            }
        }
    }
    #undef STG
}

// ---------------- feat_out[node] = feat[node] + y[batch[node]] ----------------
// Rows < Tres read normally (L3-resident across calls), rows >= Tres nt.
// Output nt-stored (never pollutes L3).
__global__ void node_add_kernel(const float4* __restrict__ feat4, const float4* __restrict__ y4,
                                const int* __restrict__ batch, float* __restrict__ out,
                                int N, int D4, int Tres) {
    int node = (int)(blockIdx.x * blockDim.y + threadIdx.y);
    if (node >= N) return;
    int t = threadIdx.x;
    int b = batch[node];
    size_t idx = (size_t)node * D4 + t;
    float4 f = (node < Tres) ? feat4[idx] : ldf4<true>(&feat4[idx]);
    float4 v = y4[(size_t)b * D4 + t];
    f32x4 r;
    r.x = f.x + v.x; r.y = f.y + v.y; r.z = f.z + v.z; r.w = f.w + v.w;
    __builtin_nontemporal_store(r, (f32x4*)(out + idx * 4));
}

extern "C" void kernel_launch(void* const* d_in, const int* in_sizes, int n_in,
                              void* d_out, int out_size, void* d_ws, size_t ws_size,
                              hipStream_t stream) {
    const float* feat  = (const float*)d_in[0];
    const float* vn    = (const float*)d_in[1];
    const float* edge  = (const float*)d_in[2];
    const int*   batch = (const int*)d_in[3];
    const float* fcW   = (const float*)d_in[5];
    const float* fcb   = (const float*)d_in[6];
    const float* pW    = (const float*)d_in[7];
    const float* pb    = (const float*)d_in[8];

    const int D = in_sizes[6];            // 768
    const int N = in_sizes[0] / D;        // 100000
    const int B = in_sizes[1] / D;        // 1024
    const int edge_elems = in_sizes[2];   // B*DE
    const int D4 = D / 4;                 // 192

    float* out_feat = (float*)d_out;
    float* out_vn   = out_feat + (size_t)N * D;
    float* out_edge = out_vn + (size_t)B * D;

    char* ws = (char*)d_ws;
    size_t off = 0;
    short* xbf  = (short*)(ws + off); off += (size_t)B * D * 2;
    short* x2bf = (short*)(ws + off); off += (size_t)B * D * 2;
    short* fcWt = (short*)(ws + off); off += (size_t)D * D * 2;
    short* pWt  = (short*)(ws + off); off += (size_t)D * D * 2;
    float* y    = (float*)(ws + off);

    // 0) weights -> transposed bf16 (once per call)
    dim3 tb(32, 8);
    dim3 tg(D / 32, D / 32, 2);
    transpose_bf16<<<tg, tb, 0, stream>>>(fcW, fcWt, pW, pWt, D);

    // 1) pool + vn add -> x (bf16), Tres-partitioned loads
    pool_kernel<<<B, PCOLS, 0, stream>>>((const float4*)feat, (const float4*)vn,
                                         batch, xbf, N, D4, T_RESIDENT);

    // 2) vn_new = vn + relu(x @ fcW + fcb) -> out_vn (f32) + x2 (bf16)
    dim3 gdim(D / 64, B / 64);
    gemm_bf<true, true, true><<<gdim, THREADS, 0, stream>>>(xbf, fcWt, fcb, vn,
                                                            out_vn, x2bf, D, D);

    // 3) y = vn_new @ pW + pb
    gemm_bf<false, false, false><<<gdim, THREADS, 0, stream>>>(x2bf, pWt, pb, nullptr,
                                                               y, nullptr, D, D);

    // 4) feat_out = feat + y[batch], Tres-partitioned reads, nt stores
    dim3 nblk(192, 2);
    node_add_kernel<<<(N + 1) / 2, nblk, 0, stream>>>((const float4*)feat, (const float4*)y,
                                                      batch, out_feat, N, D4, T_RESIDENT);

    // 5) edge passthrough
    hipMemcpyAsync(out_edge, edge, (size_t)edge_elems * sizeof(float),
                   hipMemcpyDeviceToDevice, stream);
}

// Round 14
// 175.154 us; speedup vs baseline: 1.5868x; 1.0423x over previous
//
#include <hip/hip_runtime.h>
#include <cmath>

#define THREADS 256
#define PCOLS 192         // 768 floats / 4 = 192 float4 columns
#define T_RESIDENT 72000  // feat rows < T kept L3-allocating (221 MB of 256 MB)

typedef __attribute__((ext_vector_type(8))) short bf16x8;
typedef __attribute__((ext_vector_type(4))) float f32x4;

__device__ __forceinline__ short f2bf(float f) {
    return (short)(__builtin_bit_cast(unsigned, f) >> 16);
}

typedef const __attribute__((address_space(1))) unsigned int* gas1_t;
typedef __attribute__((address_space(3))) unsigned int* las3_t;
__device__ __forceinline__ void gload16(const short* g, short* l) {
    __builtin_amdgcn_global_load_lds((gas1_t)g, (las3_t)l, 16, 0, 0);
}

__device__ __forceinline__ int lower_bound_i(const int* __restrict__ arr, int n, int val) {
    int lo = 0, hi = n;
    while (lo < hi) {
        int mid = (lo + hi) >> 1;
        if (arr[mid] < val) lo = mid + 1; else hi = mid;
    }
    return lo;
}

__device__ __forceinline__ float4 f4add(float4 a, float4 b) {
    a.x += b.x; a.y += b.y; a.z += b.z; a.w += b.w; return a;
}
__device__ __forceinline__ float4 f4fma(float4 a, float s, float4 b) {
    b.x += a.x * s; b.y += a.y * s; b.z += a.z * s; b.w += a.w * s; return b;
}

template <bool NT>
__device__ __forceinline__ float4 ldf4(const float4* p) {
    if constexpr (NT) {
        f32x4 v = __builtin_nontemporal_load((const f32x4*)p);
        float4 r; r.x = v.x; r.y = v.y; r.z = v.z; r.w = v.w; return r;
    } else {
        return *p;
    }
}

// -------- prep: z<2 -> transpose+convert weights; z==2 -> edge passthrough --------
__global__ void prep_kernel(const float* __restrict__ src0, short* __restrict__ dst0,
                            const float* __restrict__ src1, short* __restrict__ dst1,
                            int n, const float4* __restrict__ edge4,
                            float4* __restrict__ out_edge4, int edge_elems4) {
    if (blockIdx.z == 2) {
        int fb = blockIdx.y * gridDim.x + blockIdx.x;
        int t = threadIdx.y * 32 + threadIdx.x;
        int i = fb * 256 + t;
        if (i < edge_elems4) out_edge4[i] = edge4[i];
        return;
    }
    const float* src = blockIdx.z ? src1 : src0;
    short* dst = blockIdx.z ? dst1 : dst0;
    __shared__ short tile[32][33];
    int bx = blockIdx.x * 32, by = blockIdx.y * 32;
    int tx = threadIdx.x, ty = threadIdx.y;  // 32 x 8
    #pragma unroll
    for (int i = 0; i < 32; i += 8)
        tile[ty + i][tx] = f2bf(src[(size_t)(by + ty + i) * n + bx + tx]);
    __syncthreads();
    #pragma unroll
    for (int i = 0; i < 32; i += 8)
        dst[(size_t)(bx + ty + i) * n + by + tx] = tile[tx][ty + i];
}

// ---------------- pool: x_bf[g] = bf16( seg_mean(feat)*log(cnt) + vn[g] ) --------
// Rows < Tres: normal loads (allocate/stay in L3); rows >= Tres: nt loads.
template <bool NT>
__device__ __forceinline__ void accum8(const float4* __restrict__ base, int a, int b, int D4, int t,
                                       float4& a0, float4& a1, float4& a2, float4& a3,
                                       float4& a4, float4& a5, float4& a6, float4& a7) {
    const float4* __restrict__ p = base + (size_t)a * D4 + t;
    int r = a;
    for (; r + 8 <= b; r += 8) {
        float4 v0 = ldf4<NT>(p + 0 * (size_t)D4);
        float4 v1 = ldf4<NT>(p + 1 * (size_t)D4);
        float4 v2 = ldf4<NT>(p + 2 * (size_t)D4);
        float4 v3 = ldf4<NT>(p + 3 * (size_t)D4);
        float4 v4 = ldf4<NT>(p + 4 * (size_t)D4);
        float4 v5 = ldf4<NT>(p + 5 * (size_t)D4);
        float4 v6 = ldf4<NT>(p + 6 * (size_t)D4);
        float4 v7 = ldf4<NT>(p + 7 * (size_t)D4);
        a0 = f4add(a0, v0); a1 = f4add(a1, v1); a2 = f4add(a2, v2); a3 = f4add(a3, v3);
        a4 = f4add(a4, v4); a5 = f4add(a5, v5); a6 = f4add(a6, v6); a7 = f4add(a7, v7);
        p += 8 * (size_t)D4;
    }
    for (; r < b; ++r) {
        a0 = f4add(a0, ldf4<NT>(p));
        p += D4;
    }
}

__global__ void pool_kernel(const float4* __restrict__ feat4, const float4* __restrict__ vn4,
                            const int* __restrict__ batch, short* __restrict__ xbf,
                            int N, int D4, int Tres) {
    int g = blockIdx.x;
    __shared__ int s_range[2];
    if (threadIdx.x < 2) s_range[threadIdx.x] = lower_bound_i(batch, N, g + (int)threadIdx.x);
    __syncthreads();
    int lo = s_range[0], hi = s_range[1];
    int cnt = hi - lo;
    float scale = (cnt > 0) ? (logf((float)cnt) / (float)cnt) : 0.f;

    int t = threadIdx.x;
    float4 a0 = {0,0,0,0}, a1 = {0,0,0,0}, a2 = {0,0,0,0}, a3 = {0,0,0,0};
    float4 a4 = {0,0,0,0}, a5 = {0,0,0,0}, a6 = {0,0,0,0}, a7 = {0,0,0,0};

    int m = hi < Tres ? hi : (lo > Tres ? lo : Tres);  // clamp(Tres, lo, hi)
    accum8<false>(feat4, lo, m, D4, t, a0, a1, a2, a3, a4, a5, a6, a7);
    accum8<true >(feat4, m, hi, D4, t, a0, a1, a2, a3, a4, a5, a6, a7);

    float4 s = f4add(f4add(f4add(a0, a1), f4add(a2, a3)), f4add(f4add(a4, a5), f4add(a6, a7)));
    float4 vnv = vn4[(size_t)g * D4 + t];
    float4 x = f4fma(s, scale, vnv);
    short4 o;
    o.x = f2bf(x.x); o.y = f2bf(x.y); o.z = f2bf(x.z); o.w = f2bf(x.w);
    *(short4*)(xbf + ((size_t)g * D4 + t) * 4) = o;
}

// ---------------- bf16-native MFMA GEMM ----------------
template <bool RELU, bool ADD_RES, bool WRITE_BF>
__global__ __launch_bounds__(256) void gemm_bf(const short* __restrict__ A,
        const short* __restrict__ Wt, const float* __restrict__ bias,
        const float* __restrict__ res, float* __restrict__ out,
        short* __restrict__ out_bf, int Nn, int K) {
    __shared__ short lds[2][2][64 * 32];
    const int tid = threadIdx.x;
    const int lane = tid & 63;
    const int wid = tid >> 6;
    const int wr = wid >> 1, wc = wid & 1;
    const int lrow = lane & 15;
    const int kg = lane >> 4;
    const int tileM = blockIdx.y * 64;
    const int tileN = blockIdx.x * 64;
    const int nk = K / 32;

    f32x4 acc[2][2] = {};

    const int srow = tid >> 2;
    const int sci = (tid & 3) ^ (srow & 3);

    #define STG(buf, kt) do {                                                    \
        short* La = lds[buf][0];                                                 \
        short* Lb = lds[buf][1];                                                 \
        gload16(A  + (size_t)(tileM + srow) * K + (kt) * 32 + sci * 8, La + tid * 8); \
        gload16(Wt + (size_t)(tileN + srow) * K + (kt) * 32 + sci * 8, Lb + tid * 8); \
    } while (0)

    STG(0, 0);
    __syncthreads();

    for (int kt = 0; kt < nk; ++kt) {
        if (kt + 1 < nk) STG((kt + 1) & 1, kt + 1);
        const short* La = lds[kt & 1][0];
        const short* Lb = lds[kt & 1][1];
        bf16x8 a[2], b[2];
        #pragma unroll
        for (int m = 0; m < 2; ++m) {
            int row = wr * 32 + m * 16 + lrow;
            a[m] = *(const bf16x8*)(La + row * 32 + ((kg ^ (row & 3)) * 8));
        }
        #pragma unroll
        for (int n = 0; n < 2; ++n) {
            int col = wc * 32 + n * 16 + lrow;
            b[n] = *(const bf16x8*)(Lb + col * 32 + ((kg ^ (col & 3)) * 8));
        }
        #pragma unroll
        for (int m = 0; m < 2; ++m)
            #pragma unroll
            for (int n = 0; n < 2; ++n)
                acc[m][n] = __builtin_amdgcn_mfma_f32_16x16x32_bf16(a[m], b[n], acc[m][n], 0, 0, 0);
        __syncthreads();
    }

    #pragma unroll
    for (int m = 0; m < 2; ++m) {
        #pragma unroll
        for (int n = 0; n < 2; ++n) {
            int col = tileN + wc * 32 + n * 16 + lrow;
            float bv = bias[col];
            #pragma unroll
            for (int r = 0; r < 4; ++r) {
                int row = tileM + wr * 32 + m * 16 + kg * 4 + r;
                float v = acc[m][n][r] + bv;
                if (RELU) v = fmaxf(v, 0.f);
                if (ADD_RES) v += res[(size_t)row * Nn + col];
                out[(size_t)row * Nn + col] = v;
                if (WRITE_BF) out_bf[(size_t)row * Nn + col] = f2bf(v);
            }
        }
    }
    #undef STG
}

// ---------------- feat_out[node] = feat[node] + y[batch[node]] ----------------
// BACKWARD order (consume pool's L3-resident head most-recent-first) + Tres
// partition (head rows normal loads, tail rows nt). 2 nodes per thread for MLP.
// Output nt-stored.
__global__ void node_add_kernel(const float4* __restrict__ feat4, const float4* __restrict__ y4,
                                const int* __restrict__ batch, float* __restrict__ out,
                                int N, int D4, int Tres) {
    int idx = (int)(blockIdx.x * (blockDim.y * 2) + threadIdx.y * 2);
    int na = N - 1 - idx;
    if (na < 0) return;
    int nb = na - 1;
    int t = threadIdx.x;

    int ba = batch[na];
    size_t ia = (size_t)na * D4 + t;
    float4 fa = (na < Tres) ? feat4[ia] : ldf4<true>(&feat4[ia]);
    float4 va = y4[(size_t)ba * D4 + t];

    bool hb = (nb >= 0);
    float4 fb = {0,0,0,0}, vb = {0,0,0,0};
    size_t ib = 0;
    if (hb) {
        int bb = batch[nb];
        ib = (size_t)nb * D4 + t;
        fb = (nb < Tres) ? feat4[ib] : ldf4<true>(&feat4[ib]);
        vb = y4[(size_t)bb * D4 + t];
    }

    f32x4 ra;
    ra.x = fa.x + va.x; ra.y = fa.y + va.y; ra.z = fa.z + va.z; ra.w = fa.w + va.w;
    __builtin_nontemporal_store(ra, (f32x4*)(out + ia * 4));
    if (hb) {
        f32x4 rb;
        rb.x = fb.x + vb.x; rb.y = fb.y + vb.y; rb.z = fb.z + vb.z; rb.w = fb.w + vb.w;
        __builtin_nontemporal_store(rb, (f32x4*)(out + ib * 4));
    }
}

extern "C" void kernel_launch(void* const* d_in, const int* in_sizes, int n_in,
                              void* d_out, int out_size, void* d_ws, size_t ws_size,
                              hipStream_t stream) {
    const float* feat  = (const float*)d_in[0];
    const float* vn    = (const float*)d_in[1];
    const float* edge  = (const float*)d_in[2];
    const int*   batch = (const int*)d_in[3];
    const float* fcW   = (const float*)d_in[5];
    const float* fcb   = (const float*)d_in[6];
    const float* pW    = (const float*)d_in[7];
    const float* pb    = (const float*)d_in[8];

    const int D = in_sizes[6];            // 768
    const int N = in_sizes[0] / D;        // 100000
    const int B = in_sizes[1] / D;        // 1024
    const int edge_elems = in_sizes[2];   // B*DE
    const int D4 = D / 4;                 // 192

    float* out_feat = (float*)d_out;
    float* out_vn   = out_feat + (size_t)N * D;
    float* out_edge = out_vn + (size_t)B * D;

    char* ws = (char*)d_ws;
    size_t off = 0;
    short* xbf  = (short*)(ws + off); off += (size_t)B * D * 2;
    short* x2bf = (short*)(ws + off); off += (size_t)B * D * 2;
    short* fcWt = (short*)(ws + off); off += (size_t)D * D * 2;
    short* pWt  = (short*)(ws + off); off += (size_t)D * D * 2;
    float* y    = (float*)(ws + off);

    // 0) weights -> transposed bf16 + edge passthrough (single launch)
    dim3 tb(32, 8);
    dim3 tg(D / 32, D / 32, 3);
    prep_kernel<<<tg, tb, 0, stream>>>(fcW, fcWt, pW, pWt, D,
                                       (const float4*)edge, (float4*)out_edge,
                                       edge_elems / 4);

    // 1) pool + vn add -> x (bf16), Tres-partitioned loads
    pool_kernel<<<B, PCOLS, 0, stream>>>((const float4*)feat, (const float4*)vn,
                                         batch, xbf, N, D4, T_RESIDENT);

    // 2) vn_new = vn + relu(x @ fcW + fcb) -> out_vn (f32) + x2 (bf16)
    dim3 gdim(D / 64, B / 64);
    gemm_bf<true, true, true><<<gdim, THREADS, 0, stream>>>(xbf, fcWt, fcb, vn,
                                                            out_vn, x2bf, D, D);

    // 3) y = vn_new @ pW + pb
    gemm_bf<false, false, false><<<gdim, THREADS, 0, stream>>>(x2bf, pWt, pb, nullptr,
                                                               y, nullptr, D, D);

    // 4) feat_out = feat + y[batch]  (backward + Tres, 2 nodes/thread, nt stores)
    dim3 nblk(192, 2);
    node_add_kernel<<<(N + 3) / 4, nblk, 0, stream>>>((const float4*)feat, (const float4*)y,
                                                      batch, out_feat, N, D4, T_RESIDENT);
}